// Round 15
// baseline (52.845 us; speedup 1.0000x reference)
//
#include <hip/hip_runtime.h>
#include <math.h>

#define T_LEN 1024
#define PRED_LEN 256
#define OUT_T (T_LEN + PRED_LEN)
#define DM 256
#define KSEL 32
#define RTAU 1e-4f

#define PAD16(i) ((i) + ((i) >> 4))   // float2 arrays
#define C1024 0.006135923151542565f   // 2*pi/1024

// W16[e] = exp(-2*pi*i*e/16), fp32
__device__ __constant__ float W16RF[16] = {
    1.0f,  0.92387953f,  0.70710678f,  0.38268343f, 0.0f, -0.38268343f, -0.70710678f, -0.92387953f,
   -1.0f, -0.92387953f, -0.70710678f, -0.38268343f, 0.0f,  0.38268343f,  0.70710678f,  0.92387953f };
__device__ __constant__ float W16IF[16] = {
    0.0f, -0.38268343f, -0.70710678f, -0.92387953f, -1.0f, -0.92387953f, -0.70710678f, -0.38268343f,
    0.0f,  0.38268343f,  0.70710678f,  0.92387953f,  1.0f,  0.92387953f,  0.70710678f,  0.38268343f };

// ---------------- Kernel T: fp64 twiddle table (refinement only) ----------------
__global__ void fl_twiddle_kernel(double* __restrict__ gwr, double* __restrict__ gwi) {
    int e = blockIdx.x * 64 + threadIdx.x;
    double ang = (double)e * (6.283185307179586476925286766559 / 1024.0);
    gwr[e] = cos(ang);
    gwi[e] = -sin(ang);
}

// ---- 1024-pt packed FFT core, 2 chains/thread (8 waves). thread (w,lane):
// outputs X[k], k = ((w<<1)|q) + 16*rev6(lane), q = 0,1
__device__ __forceinline__ void fft1024_2(const float2* __restrict__ xin,
                                          int lane, int w, float* ar, float* ai) {
    const int f0 = (w << 1) & 3;          // wave-uniform: 0 or 2
    float Fr[4][2], Fi[4][2];
#pragma unroll
    for (int n1a = 0; n1a < 4; ++n1a) {
        float2 a  = xin[lane + 64 * (n1a + 0)];
        float2 bb = xin[lane + 64 * (n1a + 4)];
        float2 cV = xin[lane + 64 * (n1a + 8)];
        float2 d  = xin[lane + 64 * (n1a + 12)];
        float t0r = a.x + cV.x, t0i = a.y + cV.y;
        float t1r = a.x - cV.x, t1i = a.y - cV.y;
        float t2r = bb.x + d.x, t2i = bb.y + d.y;
        float t3r = bb.x - d.x, t3i = bb.y - d.y;
        if (f0 == 0) {
            Fr[n1a][0] = t0r + t2r;  Fi[n1a][0] = t0i + t2i;     // f=0
            Fr[n1a][1] = t1r + t3i;  Fi[n1a][1] = t1i - t3r;     // f=1: t1 - i*t3
        } else {
            Fr[n1a][0] = t0r - t2r;  Fi[n1a][0] = t0i - t2i;     // f=2
            Fr[n1a][1] = t1r - t3i;  Fi[n1a][1] = t1i + t3r;     // f=3: t1 + i*t3
        }
    }
#pragma unroll
    for (int q = 0; q < 2; ++q) {
        const int k1 = (w << 1) | q;
        float cr = Fr[0][q], ci = Fi[0][q];
#pragma unroll
        for (int n1a = 1; n1a < 4; ++n1a) {
            int e = (n1a * k1) & 15;
            float wr = W16RF[e], wi = W16IF[e];
            cr += Fr[n1a][q] * wr - Fi[n1a][q] * wi;
            ci += Fr[n1a][q] * wi + Fi[n1a][q] * wr;
        }
        // twiddle W1024^(lane*k1), lane*k1 <= 945
        float th = (float)(lane * k1) * C1024;
        float sn, cs; __sincosf(th, &sn, &cs);
        ar[q] = cr * cs + ci * sn;          // (cr + i ci)*(cs - i sn)
        ai[q] = ci * cs - cr * sn;
    }
#pragma unroll
    for (int s = 0; s < 6; ++s) {
        const int half = 32 >> s;
        const int e = (lane & (half - 1)) << s;          // < 32
        float th = (float)(e << 4) * C1024;              // W64^e = W1024^(16e)
        float sn, cs; __sincosf(th, &sn, &cs);
        const bool up = (lane & half) != 0;
#pragma unroll
        for (int q = 0; q < 2; ++q) {
            float orr = __shfl_xor(ar[q], half);
            float oii = __shfl_xor(ai[q], half);
            float sr = ar[q] + orr, si = ai[q] + oii;
            float dr = orr - ar[q], di = oii - ai[q];
            ar[q] = up ? (dr * cs + di * sn) : sr;
            ai[q] = up ? (di * cs - dr * sn) : si;
        }
    }
}

// ---------------- Fused: fp32 FFT + hist top-32 (bitset) + fp64 refine + inverse-FFT synthesis ----------------
// grid = 1024 blocks (one column-pair each), block = 512 threads = 8 waves; ~17.1 KB LDS.
// NO min-wave clamp: natural VGPR (~48-64) -> up to 32 waves/CU from the 4 co-resident blocks.
__global__ void __launch_bounds__(512)
fl_fused_kernel(const float* __restrict__ x,
                const double* __restrict__ gwr, const double* __restrict__ gwi,
                float* __restrict__ out) {
    __shared__ float2 spP[PAD16(1023) + 1];   // packed spectrum (padded float2)
    __shared__ char smemU[8192];              // union: xsh (FFT1 in) | {mg, hist} | Zc (FFT2 in)
    __shared__ unsigned selw[64];             // selection bitsets: [c][k>>5]
    float2* xsh  = (float2*)smemU;
    float*  mg   = (float*)smemU;             // [1024]
    int*    hist = (int*)(smemU + 4096);      // [512]

    const int tid  = threadIdx.x;
    const int lane = tid & 63;
    const int w    = tid >> 6;                // wave 0..7

    const int bid = blockIdx.x;
    const int sp  = ((bid & 7) << 7) | (bid >> 3);   // XCD-chunked, bijective over 1024
    const int b   = sp >> 7;
    const int d0  = (sp & 127) << 1;

    // load the packed column-pair into LDS
    for (int j = 0; j < 2; ++j) {
        int e = tid + (j << 9);
        xsh[e] = *reinterpret_cast<const float2*>(&x[(((size_t)(b << 10) + e) << 8) + d0]);
    }
    if (tid < 64) selw[tid] = 0u;
    __syncthreads();

    // ---- FFT 1: forward transform of packed pair (2 chains/thread)
    float ar[2], ai[2];
    fft1024_2(xsh, lane, w, ar, ai);

    const int krev = (int)(__brev((unsigned)lane) >> 26);  // rev6(lane)
#pragma unroll
    for (int q = 0; q < 2; ++q) {
        int k = ((w << 1) | q) + (krev << 4);
        spP[PAD16(k)] = float2{ ar[q], ai[q] };
    }
    __syncthreads();   // xsh reads + spP writes all complete

    // ---- magnitudes for both packed columns (conjugate-symmetry unpack); overwrites xsh
    {
        int m = tid & 511;                 // 512 threads cover m = 0..511 once
        int n = (1024 - m) & 1023;
        float2 Pk = spP[PAD16(m)];
        float2 Pn = spP[PAD16(n)];
        float rr0 = 0.5f * (Pk.x + Pn.x), ii0 = 0.5f * (Pk.y - Pn.y);
        float rr1 = 0.5f * (Pk.y + Pn.y), ii1 = 0.5f * (Pn.x - Pk.x);
        mg[m]       = rr0 * rr0 + ii0 * ii0;
        mg[512 + m] = rr1 * rr1 + ii1 * ii1;
    }
    __syncthreads();

    // ---- histogram top-32 (waves 0,1: one wave per column) + fp64 boundary refinement
    if (tid < 128) {
        const int c = tid >> 6;
        const float* mgc = mg + (c << 9);
        int* histc = hist + (c << 8);

        float v[8]; int hiw[8];
#pragma unroll
        for (int q = 0; q < 8; ++q) v[q] = mgc[(q << 6) | lane];
        if (lane == 0) v[0] = -1.0f;   // exclude m=0; m=512 excluded by range
#pragma unroll
        for (int q = 0; q < 8; ++q) hiw[q] = __float_as_int(v[q]);

        int mx = hiw[0];
#pragma unroll
        for (int q = 1; q < 8; ++q) mx = max(mx, hiw[q]);
#pragma unroll
        for (int off = 1; off < 64; off <<= 1) mx = max(mx, __shfl_xor(mx, off));

        const int base = (mx >> 20) - 250;
        int idx[8];
#pragma unroll
        for (int q = 0; q < 8; ++q) {
            int t = (hiw[q] >> 20) - base;
            idx[q] = t < 0 ? 0 : t;
        }

        *reinterpret_cast<int4*>(&histc[lane << 2]) = int4{0, 0, 0, 0};
#pragma unroll
        for (int q = 0; q < 8; ++q) atomicAdd(&histc[idx[q]], 1);

        int4 cc = *reinterpret_cast<int4*>(&histc[lane << 2]);
        int s_local = cc.x + cc.y + cc.z + cc.w;

        int s = s_local;
#pragma unroll
        for (int off = 1; off < 64; off <<= 1) {
            int t = __shfl_down(s, off);
            if (lane + off < 64) s += t;
        }
        const int S_gt = s - s_local;
        const int A3 = S_gt;
        const int A2 = A3 + cc.w;
        const int A1 = A2 + cc.z;
        const int A0 = A1 + cc.y;

        int foundB = -1, foundR = 0;
        if (A0 < KSEL && A0 + cc.x >= KSEL) { foundB = (lane << 2) | 0; foundR = KSEL - A0; }
        if (A1 < KSEL && A1 + cc.y >= KSEL) { foundB = (lane << 2) | 1; foundR = KSEL - A1; }
        if (A2 < KSEL && A2 + cc.z >= KSEL) { foundB = (lane << 2) | 2; foundR = KSEL - A2; }
        if (A3 < KSEL && A3 + cc.w >= KSEL) { foundB = (lane << 2) | 3; foundR = KSEL - A3; }

        unsigned long long fm = __ballot(foundB >= 0);
        const int srcB = (int)(__ffsll((unsigned long long)fm) - 1);
        const int B = __shfl(foundB, srcB);
        const int r = __shfl(foundR, srcB);

        unsigned selmask = 0, candmask = 0;
#pragma unroll
        for (int q = 0; q < 8; ++q) {
            if (idx[q] > B) selmask |= (1u << q);
            else if (idx[q] == B) candmask |= (1u << q);
        }

        for (int it = 0; it < r; ++it) {
            float bv = -2.0f; int bq = -1;
#pragma unroll
            for (int q = 0; q < 8; ++q) {
                bool cand = ((candmask >> q) & 1u) != 0;
                if (cand && v[q] > bv) { bv = v[q]; bq = q; }
            }
            int bi = (bq < 0) ? 0x7FFFFFFF : ((bq << 6) | lane);
#pragma unroll
            for (int off = 1; off < 64; off <<= 1) {
                float ov = __shfl_xor(bv, off);
                int   oi = __shfl_xor(bi, off);
                if (ov > bv || (ov == bv && oi < bi)) { bv = ov; bi = oi; }
            }
            if (bi != 0x7FFFFFFF && lane == (bi & 63)) {
                unsigned bit = 1u << (bi >> 6);
                selmask  |= bit;
                candmask &= ~bit;
            }
        }

        // ---- fp64 refinement when the rank-32/33 fp32 gap is too small (reads x from global)
        {
            float vminS = 3.0e38f, vmaxU = -3.0e38f;
#pragma unroll
            for (int q = 0; q < 8; ++q) {
                if ((selmask >> q) & 1u) vminS = fminf(vminS, v[q]);
                else                     vmaxU = fmaxf(vmaxU, v[q]);
            }
#pragma unroll
            for (int off = 1; off < 64; off <<= 1) {
                vminS = fminf(vminS, __shfl_xor(vminS, off));
                vmaxU = fmaxf(vmaxU, __shfl_xor(vmaxU, off));
            }
            const float tau = RTAU * vminS;
            if (vminS - vmaxU < tau) {            // wave-uniform, rare
                const float lo = vmaxU - tau, hi = vminS + tau;
                unsigned candq = 0; int nAbove = 0;
#pragma unroll
                for (int q = 0; q < 8; ++q) {
                    bool inw = (v[q] >= lo) && (v[q] <= hi);
                    if (inw) candq |= (1u << q);
                    if (((selmask >> q) & 1u) && v[q] > hi) ++nAbove;
                }
#pragma unroll
                for (int off = 1; off < 64; off <<= 1) nAbove += __shfl_xor(nAbove, off);
                const int kneed = KSEL - nAbove;
                selmask &= ~candq;                 // drop window members; re-pick in fp64

                const float* xcol = x + ((size_t)(b << 10) << 8) + d0 + c;
                double sV = -1.0; int sSrc = 0; int cnum = 0;
                for (int q = 0; q < 8; ++q) {
                    unsigned long long bal = __ballot((candq >> q) & 1u);
                    while (bal) {
                        int srcl = (int)(__ffsll(bal) - 1);
                        bal &= bal - 1;
                        int m = (q << 6) | srcl;
                        double sr = 0.0, si = 0.0;
                        for (int u = 0; u < 16; ++u) {
                            int n = lane + (u << 6);
                            double xvd = (double)xcol[(size_t)n << 8];
                            int e = (m * n) & 1023;
                            sr = fma(xvd, gwr[e], sr);
                            si = fma(xvd, gwi[e], si);
                        }
#pragma unroll
                        for (int off = 1; off < 64; off <<= 1) {
                            sr += __shfl_xor(sr, off);
                            si += __shfl_xor(si, off);
                        }
                        if (lane == cnum) { sV = sr * sr + si * si; sSrc = (q << 6) | srcl; }
                        ++cnum;
                        if (cnum >= 64) break;
                    }
                    if (cnum >= 64) break;
                }
                for (int it = 0; it < kneed; ++it) {
                    double bv = sV; int bl = lane;
#pragma unroll
                    for (int off = 1; off < 64; off <<= 1) {
                        double ov = __shfl_xor(bv, off);
                        int    ol = __shfl_xor(bl, off);
                        if (ov > bv || (ov == bv && ol < bl)) { bv = ov; bl = ol; }
                    }
                    int wsrc = __shfl(sSrc, bl);
                    if (lane == (wsrc & 63)) selmask |= 1u << (wsrc >> 6);
                    if (lane == bl) sV = -2.0;
                }
            }
        }

        // ---- write selection bits (m and its conjugate mirror 1024-m)
#pragma unroll
        for (int q = 0; q < 8; ++q) {
            if ((selmask >> q) & 1u) {
                int m  = (q << 6) | lane;          // 1..511
                int mm = 1024 - m;                 // 513..1023
                atomicOr(&selw[(c << 5) | (m  >> 5)], 1u << (m  & 31));
                atomicOr(&selw[(c << 5) | (mm >> 5)], 1u << (mm & 31));
            }
        }
    }
    __syncthreads();

    // ---- build conj(Z) into smemU: Z[k] = s0*X0[k] + i*s1*X1[k]; Zc = (Z.r, -Z.i)
    {
        float2* zc = (float2*)smemU;
#pragma unroll
        for (int jj = 0; jj < 2; ++jj) {
            int k = tid + (jj << 9);
            int n = (1024 - k) & 1023;
            float2 Pk = spP[PAD16(k)];
            float2 Pn = spP[PAD16(n)];
            float X0r = 0.5f * (Pk.x + Pn.x), X0i = 0.5f * (Pk.y - Pn.y);
            float X1r = 0.5f * (Pk.y + Pn.y), X1i = 0.5f * (Pn.x - Pk.x);
            bool s0 = (selw[(k >> 5)]      >> (k & 31)) & 1u;
            bool s1 = (selw[32 + (k >> 5)] >> (k & 31)) & 1u;
            float Zr = (s0 ? X0r : 0.0f) - (s1 ? X1i : 0.0f);
            float Zi = (s0 ? X0i : 0.0f) + (s1 ? X1r : 0.0f);
            zc[k] = float2{ Zr, -Zi };
        }
    }
    __syncthreads();

    // ---- FFT 2 (inverse via conjugation): R[t] = DFT(conj(Z))[t] = conj(1024*y[t])
    fft1024_2(xsh, lane, w, ar, ai);

    // ---- write y: out0 = Re(R)/1024, out1 = -Im(R)/1024; duplicate t<256 to t+1024
    {
        const float S = 1.0f / 1024.0f;
        float2* o2 = reinterpret_cast<float2*>(out + (size_t)b * OUT_T * DM + d0);
#pragma unroll
        for (int q = 0; q < 2; ++q) {
            int t = ((w << 1) | q) + (krev << 4);
            float2 o{ ar[q] * S, -ai[q] * S };
            o2[(size_t)t * 128] = o;
            if (t < PRED_LEN) o2[(size_t)(t + T_LEN) * 128] = o;
        }
    }
}

extern "C" void kernel_launch(void* const* d_in, const int* in_sizes, int n_in,
                              void* d_out, int out_size, void* d_ws, size_t ws_size,
                              hipStream_t stream) {
    const float* x = (const float*)d_in[0];
    float* out = (float*)d_out;

    char* w = (char*)d_ws;
    double* gwr = (double*)(w);
    double* gwi = (double*)(w + 1024 * sizeof(double));

    hipLaunchKernelGGL(fl_twiddle_kernel, dim3(16), dim3(64), 0, stream, gwr, gwi);
    hipLaunchKernelGGL(fl_fused_kernel, dim3(1024), dim3(512), 0, stream,
                       x, gwr, gwi, out);
}

// Round 16
// 42.758 us; speedup vs baseline: 1.2359x; 1.2359x over previous
//
#include <hip/hip_runtime.h>
#include <math.h>

#define T_LEN 1024
#define PRED_LEN 256
#define OUT_T (T_LEN + PRED_LEN)
#define DM 256
#define KSEL 32
#define RTAU 1e-4f

#define PAD16(i) ((i) + ((i) >> 4))   // float2 arrays

// W16[e] = exp(-2*pi*i*e/16), fp32
__device__ __constant__ float W16RF[16] = {
    1.0f,  0.92387953f,  0.70710678f,  0.38268343f, 0.0f, -0.38268343f, -0.70710678f, -0.92387953f,
   -1.0f, -0.92387953f, -0.70710678f, -0.38268343f, 0.0f,  0.38268343f,  0.70710678f,  0.92387953f };
__device__ __constant__ float W16IF[16] = {
    0.0f, -0.38268343f, -0.70710678f, -0.92387953f, -1.0f, -0.92387953f, -0.70710678f, -0.38268343f,
    0.0f,  0.38268343f,  0.70710678f,  0.92387953f,  1.0f,  0.92387953f,  0.70710678f,  0.38268343f };

// ---------------- Kernel T: twiddle tables W[e] = exp(-2pi*i*e/1024), fp64 + packed fp32 ----------------
__global__ void fl_twiddle_kernel(double* __restrict__ gwr, double* __restrict__ gwi,
                                  float2* __restrict__ gwF) {
    int e = blockIdx.x * 64 + threadIdx.x;
    double ang = (double)e * (6.283185307179586476925286766559 / 1024.0);
    double c = cos(ang), s = -sin(ang);
    gwr[e] = c; gwi[e] = s;
    gwF[e] = float2{ (float)c, (float)s };
}

// ---- 1024-pt packed FFT core (16x64 four-step), LDS float2 twiddle table ----
// thread (w, lane): outputs X[k], k = ((w<<2)|q) + 16*rev6(lane)
__device__ __forceinline__ void fft1024(const float2* __restrict__ xin,
                                        const float2* __restrict__ twF,
                                        int lane, int w, float* ar, float* ai) {
    float Fr[4][4], Fi[4][4];
#pragma unroll
    for (int n1a = 0; n1a < 4; ++n1a) {
        float2 a  = xin[lane + 64 * (n1a + 0)];
        float2 bb = xin[lane + 64 * (n1a + 4)];
        float2 cV = xin[lane + 64 * (n1a + 8)];
        float2 d  = xin[lane + 64 * (n1a + 12)];
        float t0r = a.x + cV.x, t0i = a.y + cV.y;
        float t1r = a.x - cV.x, t1i = a.y - cV.y;
        float t2r = bb.x + d.x, t2i = bb.y + d.y;
        float t3r = bb.x - d.x, t3i = bb.y - d.y;
        Fr[n1a][0] = t0r + t2r;  Fi[n1a][0] = t0i + t2i;
        Fr[n1a][2] = t0r - t2r;  Fi[n1a][2] = t0i - t2i;
        Fr[n1a][1] = t1r + t3i;  Fi[n1a][1] = t1i - t3r;   // t1 - i*t3
        Fr[n1a][3] = t1r - t3i;  Fi[n1a][3] = t1i + t3r;   // t1 + i*t3
    }
#pragma unroll
    for (int q = 0; q < 4; ++q) {
        const int k1 = (w << 2) | q;
        float cr = Fr[0][q], ci = Fi[0][q];
#pragma unroll
        for (int n1a = 1; n1a < 4; ++n1a) {
            int e = (n1a * k1) & 15;
            float wr = W16RF[e], wi = W16IF[e];
            cr += Fr[n1a][q] * wr - Fi[n1a][q] * wi;
            ci += Fr[n1a][q] * wi + Fi[n1a][q] * wr;
        }
        float2 tw = twF[PAD16((lane * k1) & 1023)];
        ar[q] = cr * tw.x - ci * tw.y;
        ai[q] = cr * tw.y + ci * tw.x;
    }
#pragma unroll
    for (int s = 0; s < 6; ++s) {
        const int half = 32 >> s;
        const int e = (lane & (half - 1)) << s;          // < 32
        float2 tw = twF[PAD16(e << 4)];                  // W64^e = W1024^(16e)
        const bool up = (lane & half) != 0;
#pragma unroll
        for (int q = 0; q < 4; ++q) {
            float orr = __shfl_xor(ar[q], half);
            float oii = __shfl_xor(ai[q], half);
            float sr = ar[q] + orr, si = ai[q] + oii;
            float dr = orr - ar[q], di = oii - ai[q];
            ar[q] = up ? (dr * tw.x - di * tw.y) : sr;
            ai[q] = up ? (dr * tw.y + di * tw.x) : si;
        }
    }
}

// ---------------- Fused: fp32 FFT + hist top-32 (bitset) + fp64 refine + inverse-FFT synthesis ----------------
// grid = 1024 blocks (one column-pair each), block = 256 threads = 4 waves.
__global__ void __launch_bounds__(256, 4)
fl_fused_kernel(const float* __restrict__ x,
                const double* __restrict__ gwr, const double* __restrict__ gwi,
                const float2* __restrict__ gwF, float* __restrict__ out) {
    __shared__ float2 twF[PAD16(1023) + 1];   // fp32 twiddle table (persists)
    __shared__ float2 spP[PAD16(1023) + 1];   // packed spectrum
    __shared__ char smemU[8192];              // union: xsh (FFT1 in) | {mg, hist} | Zc (FFT2 in)
    __shared__ unsigned selw[64];             // selection bitsets: [c][k>>5]
    float2* xsh  = (float2*)smemU;
    float*  mg   = (float*)smemU;             // [1024]
    int*    hist = (int*)(smemU + 4096);      // [512]

    const int tid  = threadIdx.x;
    const int lane = tid & 63;
    const int w    = tid >> 6;

    const int bid = blockIdx.x;
    const int sp  = ((bid & 7) << 7) | (bid >> 3);   // XCD-chunked, bijective over 1024
    const int b   = sp >> 7;
    const int d0  = (sp & 127) << 1;

    // stage fp32 twiddles (padded float2) and the packed column-pair into LDS
    for (int j = 0; j < 4; ++j) {
        int e = tid + (j << 8);
        twF[PAD16(e)] = gwF[e];
        xsh[e] = *reinterpret_cast<const float2*>(&x[(((size_t)(b << 10) + e) << 8) + d0]);
    }
    if (tid < 64) selw[tid] = 0u;
    __syncthreads();

    // ---- FFT 1: forward transform of packed pair
    float ar[4], ai[4];
    fft1024(xsh, twF, lane, w, ar, ai);

    const int krev = (int)(__brev((unsigned)lane) >> 26);  // rev6(lane)
#pragma unroll
    for (int q = 0; q < 4; ++q) {
        int k = ((w << 2) | q) + (krev << 4);
        spP[PAD16(k)] = float2{ ar[q], ai[q] };
    }
    __syncthreads();   // xsh reads + spP writes complete (merged barrier)

    // ---- magnitudes for both packed columns (conjugate-symmetry unpack); overwrites xsh
#pragma unroll
    for (int h = 0; h < 2; ++h) {
        int m = tid + (h << 8);
        int n = (1024 - m) & 1023;
        float2 Pk = spP[PAD16(m)];
        float2 Pn = spP[PAD16(n)];
        float rr0 = 0.5f * (Pk.x + Pn.x), ii0 = 0.5f * (Pk.y - Pn.y);
        float rr1 = 0.5f * (Pk.y + Pn.y), ii1 = 0.5f * (Pn.x - Pk.x);
        mg[m]       = rr0 * rr0 + ii0 * ii0;
        mg[512 + m] = rr1 * rr1 + ii1 * ii1;
    }
    __syncthreads();

    // ---- histogram top-32 (waves 0,1: one wave per column) + fp64 boundary refinement
    if (tid < 128) {
        const int c = tid >> 6;
        const float* mgc = mg + (c << 9);
        int* histc = hist + (c << 8);

        float v[8]; int hiw[8];
#pragma unroll
        for (int q = 0; q < 8; ++q) v[q] = mgc[(q << 6) | lane];
        if (lane == 0) v[0] = -1.0f;   // exclude m=0; m=512 excluded by range
#pragma unroll
        for (int q = 0; q < 8; ++q) hiw[q] = __float_as_int(v[q]);

        int mx = hiw[0];
#pragma unroll
        for (int q = 1; q < 8; ++q) mx = max(mx, hiw[q]);
#pragma unroll
        for (int off = 1; off < 64; off <<= 1) mx = max(mx, __shfl_xor(mx, off));

        const int base = (mx >> 20) - 250;
        int idx[8];
#pragma unroll
        for (int q = 0; q < 8; ++q) {
            int t = (hiw[q] >> 20) - base;
            idx[q] = t < 0 ? 0 : t;
        }

        *reinterpret_cast<int4*>(&histc[lane << 2]) = int4{0, 0, 0, 0};
#pragma unroll
        for (int q = 0; q < 8; ++q) atomicAdd(&histc[idx[q]], 1);

        int4 cc = *reinterpret_cast<int4*>(&histc[lane << 2]);
        int s_local = cc.x + cc.y + cc.z + cc.w;

        int s = s_local;
#pragma unroll
        for (int off = 1; off < 64; off <<= 1) {
            int t = __shfl_down(s, off);
            if (lane + off < 64) s += t;
        }
        const int S_gt = s - s_local;
        const int A3 = S_gt;
        const int A2 = A3 + cc.w;
        const int A1 = A2 + cc.z;
        const int A0 = A1 + cc.y;

        int foundB = -1, foundR = 0;
        if (A0 < KSEL && A0 + cc.x >= KSEL) { foundB = (lane << 2) | 0; foundR = KSEL - A0; }
        if (A1 < KSEL && A1 + cc.y >= KSEL) { foundB = (lane << 2) | 1; foundR = KSEL - A1; }
        if (A2 < KSEL && A2 + cc.z >= KSEL) { foundB = (lane << 2) | 2; foundR = KSEL - A2; }
        if (A3 < KSEL && A3 + cc.w >= KSEL) { foundB = (lane << 2) | 3; foundR = KSEL - A3; }

        unsigned long long fm = __ballot(foundB >= 0);
        const int srcB = (int)(__ffsll((unsigned long long)fm) - 1);
        const int B = __shfl(foundB, srcB);
        const int r = __shfl(foundR, srcB);

        unsigned selmask = 0, candmask = 0;
#pragma unroll
        for (int q = 0; q < 8; ++q) {
            if (idx[q] > B) selmask |= (1u << q);
            else if (idx[q] == B) candmask |= (1u << q);
        }

        for (int it = 0; it < r; ++it) {
            float bv = -2.0f; int bq = -1;
#pragma unroll
            for (int q = 0; q < 8; ++q) {
                bool cand = ((candmask >> q) & 1u) != 0;
                if (cand && v[q] > bv) { bv = v[q]; bq = q; }
            }
            int bi = (bq < 0) ? 0x7FFFFFFF : ((bq << 6) | lane);
#pragma unroll
            for (int off = 1; off < 64; off <<= 1) {
                float ov = __shfl_xor(bv, off);
                int   oi = __shfl_xor(bi, off);
                if (ov > bv || (ov == bv && oi < bi)) { bv = ov; bi = oi; }
            }
            if (bi != 0x7FFFFFFF && lane == (bi & 63)) {
                unsigned bit = 1u << (bi >> 6);
                selmask  |= bit;
                candmask &= ~bit;
            }
        }

        // ---- fp64 refinement when the rank-32/33 fp32 gap is too small (reads x from global)
        {
            float vminS = 3.0e38f, vmaxU = -3.0e38f;
#pragma unroll
            for (int q = 0; q < 8; ++q) {
                if ((selmask >> q) & 1u) vminS = fminf(vminS, v[q]);
                else                     vmaxU = fmaxf(vmaxU, v[q]);
            }
#pragma unroll
            for (int off = 1; off < 64; off <<= 1) {
                vminS = fminf(vminS, __shfl_xor(vminS, off));
                vmaxU = fmaxf(vmaxU, __shfl_xor(vmaxU, off));
            }
            const float tau = RTAU * vminS;
            if (vminS - vmaxU < tau) {            // wave-uniform, rare
                const float lo = vmaxU - tau, hi = vminS + tau;
                unsigned candq = 0; int nAbove = 0;
#pragma unroll
                for (int q = 0; q < 8; ++q) {
                    bool inw = (v[q] >= lo) && (v[q] <= hi);
                    if (inw) candq |= (1u << q);
                    if (((selmask >> q) & 1u) && v[q] > hi) ++nAbove;
                }
#pragma unroll
                for (int off = 1; off < 64; off <<= 1) nAbove += __shfl_xor(nAbove, off);
                const int kneed = KSEL - nAbove;
                selmask &= ~candq;                 // drop window members; re-pick in fp64

                const float* xcol = x + ((size_t)(b << 10) << 8) + d0 + c;
                double sV = -1.0; int sSrc = 0; int cnum = 0;
                for (int q = 0; q < 8; ++q) {
                    unsigned long long bal = __ballot((candq >> q) & 1u);
                    while (bal) {
                        int srcl = (int)(__ffsll(bal) - 1);
                        bal &= bal - 1;
                        int m = (q << 6) | srcl;
                        double sr = 0.0, si = 0.0;
                        for (int u = 0; u < 16; ++u) {
                            int n = lane + (u << 6);
                            double xvd = (double)xcol[(size_t)n << 8];
                            int e = (m * n) & 1023;
                            sr = fma(xvd, gwr[e], sr);
                            si = fma(xvd, gwi[e], si);
                        }
#pragma unroll
                        for (int off = 1; off < 64; off <<= 1) {
                            sr += __shfl_xor(sr, off);
                            si += __shfl_xor(si, off);
                        }
                        if (lane == cnum) { sV = sr * sr + si * si; sSrc = (q << 6) | srcl; }
                        ++cnum;
                        if (cnum >= 64) break;
                    }
                    if (cnum >= 64) break;
                }
                for (int it = 0; it < kneed; ++it) {
                    double bv = sV; int bl = lane;
#pragma unroll
                    for (int off = 1; off < 64; off <<= 1) {
                        double ov = __shfl_xor(bv, off);
                        int    ol = __shfl_xor(bl, off);
                        if (ov > bv || (ov == bv && ol < bl)) { bv = ov; bl = ol; }
                    }
                    int wsrc = __shfl(sSrc, bl);
                    if (lane == (wsrc & 63)) selmask |= 1u << (wsrc >> 6);
                    if (lane == bl) sV = -2.0;
                }
            }
        }

        // ---- write selection bits (m and its conjugate mirror 1024-m)
#pragma unroll
        for (int q = 0; q < 8; ++q) {
            if ((selmask >> q) & 1u) {
                int m  = (q << 6) | lane;          // 1..511
                int mm = 1024 - m;                 // 513..1023
                atomicOr(&selw[(c << 5) | (m  >> 5)], 1u << (m  & 31));
                atomicOr(&selw[(c << 5) | (mm >> 5)], 1u << (mm & 31));
            }
        }
    }
    __syncthreads();

    // ---- build conj(Z) into smemU: Z[k] = s0*X0[k] + i*s1*X1[k]; Zc = (Z.r, -Z.i)
    {
        float2* zc = (float2*)smemU;
#pragma unroll
        for (int jj = 0; jj < 4; ++jj) {
            int k = tid + (jj << 8);
            int n = (1024 - k) & 1023;
            float2 Pk = spP[PAD16(k)];
            float2 Pn = spP[PAD16(n)];
            float X0r = 0.5f * (Pk.x + Pn.x), X0i = 0.5f * (Pk.y - Pn.y);
            float X1r = 0.5f * (Pk.y + Pn.y), X1i = 0.5f * (Pn.x - Pk.x);
            bool s0 = (selw[(k >> 5)]      >> (k & 31)) & 1u;
            bool s1 = (selw[32 + (k >> 5)] >> (k & 31)) & 1u;
            float Zr = (s0 ? X0r : 0.0f) - (s1 ? X1i : 0.0f);
            float Zi = (s0 ? X0i : 0.0f) + (s1 ? X1r : 0.0f);
            zc[k] = float2{ Zr, -Zi };
        }
    }
    __syncthreads();

    // ---- FFT 2 (inverse via conjugation): R[t] = DFT(conj(Z))[t] = conj(1024*y[t])
    fft1024(xsh, twF, lane, w, ar, ai);

    // ---- write y: out0 = Re(R)/1024, out1 = -Im(R)/1024; duplicate t<256 to t+1024
    {
        const float S = 1.0f / 1024.0f;
        float2* o2 = reinterpret_cast<float2*>(out + (size_t)b * OUT_T * DM + d0);
#pragma unroll
        for (int q = 0; q < 4; ++q) {
            int t = ((w << 2) | q) + (krev << 4);
            float2 o{ ar[q] * S, -ai[q] * S };
            o2[(size_t)t * 128] = o;
            if (t < PRED_LEN) o2[(size_t)(t + T_LEN) * 128] = o;
        }
    }
}

extern "C" void kernel_launch(void* const* d_in, const int* in_sizes, int n_in,
                              void* d_out, int out_size, void* d_ws, size_t ws_size,
                              hipStream_t stream) {
    const float* x = (const float*)d_in[0];
    float* out = (float*)d_out;

    char* w = (char*)d_ws;
    double* gwr = (double*)(w);
    double* gwi = (double*)(w + 1024 * sizeof(double));
    float2* gwF = (float2*)(w + 2048 * sizeof(double));

    hipLaunchKernelGGL(fl_twiddle_kernel, dim3(16), dim3(64), 0, stream, gwr, gwi, gwF);
    hipLaunchKernelGGL(fl_fused_kernel, dim3(1024), dim3(256), 0, stream,
                       x, gwr, gwi, gwF, out);
}

// Round 17
// 40.809 us; speedup vs baseline: 1.2950x; 1.0478x over previous
//
#include <hip/hip_runtime.h>
#include <math.h>

#define T_LEN 1024
#define PRED_LEN 256
#define OUT_T (T_LEN + PRED_LEN)
#define DM 256
#define KSEL 32
#define RTAU 1e-4f

#define PAD16(i) ((i) + ((i) >> 4))   // float2 arrays

// W16[e] = exp(-2*pi*i*e/16), fp32
__device__ __constant__ float W16RF[16] = {
    1.0f,  0.92387953f,  0.70710678f,  0.38268343f, 0.0f, -0.38268343f, -0.70710678f, -0.92387953f,
   -1.0f, -0.92387953f, -0.70710678f, -0.38268343f, 0.0f,  0.38268343f,  0.70710678f,  0.92387953f };
__device__ __constant__ float W16IF[16] = {
    0.0f, -0.38268343f, -0.70710678f, -0.92387953f, -1.0f, -0.92387953f, -0.70710678f, -0.38268343f,
    0.0f,  0.38268343f,  0.70710678f,  0.92387953f,  1.0f,  0.92387953f,  0.70710678f,  0.38268343f };

// ---------------- Kernel T: twiddle tables W[e] = exp(-2pi*i*e/1024), fp64 + packed fp32 ----------------
__global__ void fl_twiddle_kernel(double* __restrict__ gwr, double* __restrict__ gwi,
                                  float2* __restrict__ gwF) {
    int e = blockIdx.x * 64 + threadIdx.x;
    double ang = (double)e * (6.283185307179586476925286766559 / 1024.0);
    double c = cos(ang), s = -sin(ang);
    gwr[e] = c; gwi[e] = s;
    gwF[e] = float2{ (float)c, (float)s };
}

// ---- 1024-pt packed FFT core (16x64 four-step), LDS float2 twiddle table ----
// thread (w, lane): outputs X[k], k = ((w<<2)|q) + 16*rev6(lane)
// PADDED: whether xin uses PAD16 indexing.
template<bool PADDED>
__device__ __forceinline__ void fft1024(const float2* __restrict__ xin,
                                        const float2* __restrict__ twF,
                                        int lane, int w, float* ar, float* ai) {
    float Fr[4][4], Fi[4][4];
#pragma unroll
    for (int n1a = 0; n1a < 4; ++n1a) {
        int i0 = lane + 64 * (n1a + 0);
        int i1 = lane + 64 * (n1a + 4);
        int i2 = lane + 64 * (n1a + 8);
        int i3 = lane + 64 * (n1a + 12);
        float2 a  = xin[PADDED ? PAD16(i0) : i0];
        float2 bb = xin[PADDED ? PAD16(i1) : i1];
        float2 cV = xin[PADDED ? PAD16(i2) : i2];
        float2 d  = xin[PADDED ? PAD16(i3) : i3];
        float t0r = a.x + cV.x, t0i = a.y + cV.y;
        float t1r = a.x - cV.x, t1i = a.y - cV.y;
        float t2r = bb.x + d.x, t2i = bb.y + d.y;
        float t3r = bb.x - d.x, t3i = bb.y - d.y;
        Fr[n1a][0] = t0r + t2r;  Fi[n1a][0] = t0i + t2i;
        Fr[n1a][2] = t0r - t2r;  Fi[n1a][2] = t0i - t2i;
        Fr[n1a][1] = t1r + t3i;  Fi[n1a][1] = t1i - t3r;   // t1 - i*t3
        Fr[n1a][3] = t1r - t3i;  Fi[n1a][3] = t1i + t3r;   // t1 + i*t3
    }
#pragma unroll
    for (int q = 0; q < 4; ++q) {
        const int k1 = (w << 2) | q;
        float cr = Fr[0][q], ci = Fi[0][q];
#pragma unroll
        for (int n1a = 1; n1a < 4; ++n1a) {
            int e = (n1a * k1) & 15;
            float wr = W16RF[e], wi = W16IF[e];
            cr += Fr[n1a][q] * wr - Fi[n1a][q] * wi;
            ci += Fr[n1a][q] * wi + Fi[n1a][q] * wr;
        }
        float2 tw = twF[PAD16((lane * k1) & 1023)];
        ar[q] = cr * tw.x - ci * tw.y;
        ai[q] = cr * tw.y + ci * tw.x;
    }
#pragma unroll
    for (int s = 0; s < 6; ++s) {
        const int half = 32 >> s;
        const int e = (lane & (half - 1)) << s;          // < 32
        float2 tw = twF[PAD16(e << 4)];                  // W64^e = W1024^(16e)
        const bool up = (lane & half) != 0;
#pragma unroll
        for (int q = 0; q < 4; ++q) {
            float orr = __shfl_xor(ar[q], half);
            float oii = __shfl_xor(ai[q], half);
            float sr = ar[q] + orr, si = ai[q] + oii;
            float dr = orr - ar[q], di = oii - ai[q];
            ar[q] = up ? (dr * tw.x - di * tw.y) : sr;
            ai[q] = up ? (dr * tw.y + di * tw.x) : si;
        }
    }
}

// ---------------- Fused: fp32 FFT + overlapped {top-32 | unpack} + fp64 refine + inverse-FFT ----------------
// grid = 1024 blocks (one column-pair each), block = 256 threads = 4 waves.
__global__ void __launch_bounds__(256, 4)
fl_fused_kernel(const float* __restrict__ x,
                const double* __restrict__ gwr, const double* __restrict__ gwi,
                const float2* __restrict__ gwF, float* __restrict__ out) {
    __shared__ float2 twF[PAD16(1023) + 1];   // fp32 twiddle table (persists)
    __shared__ float2 spP[PAD16(1023) + 1];   // packed spectrum -> later conj(Z)
    __shared__ char smemU[8192];              // union: xsh (FFT1 in) | xunp {X0[512], X1[512]}
    __shared__ int hist[512];                 // 256 bins per column
    __shared__ unsigned selw[32];             // selection bitsets: [c][m>>5], m in 0..511
    float2* xsh  = (float2*)smemU;
    float2* xunp = (float2*)smemU;            // X0 at [0..511], X1 at [512..1023]

    const int tid  = threadIdx.x;
    const int lane = tid & 63;
    const int w    = tid >> 6;

    const int bid = blockIdx.x;
    const int sp  = ((bid & 7) << 7) | (bid >> 3);   // XCD-chunked, bijective over 1024
    const int b   = sp >> 7;
    const int d0  = (sp & 127) << 1;

    // stage fp32 twiddles (padded float2) and the packed column-pair into LDS
    for (int j = 0; j < 4; ++j) {
        int e = tid + (j << 8);
        twF[PAD16(e)] = gwF[e];
        xsh[e] = *reinterpret_cast<const float2*>(&x[(((size_t)(b << 10) + e) << 8) + d0]);
    }
    if (tid < 32) selw[tid] = 0u;
    __syncthreads();                                   // barrier 1

    // ---- FFT 1: forward transform of packed pair
    float ar[4], ai[4];
    fft1024<false>(xsh, twF, lane, w, ar, ai);

    const int krev = (int)(__brev((unsigned)lane) >> 26);  // rev6(lane)
#pragma unroll
    for (int q = 0; q < 4; ++q) {
        int k = ((w << 2) | q) + (krev << 4);
        spP[PAD16(k)] = float2{ ar[q], ai[q] };
    }
    __syncthreads();                                   // barrier 2

    // ---- divergent phase: waves 0,1 do top-k; waves 2,3 unpack X0/X1 into xunp
    if (tid < 128) {
        const int c = tid >> 6;
        int* histc = hist + (c << 8);

        // magnitudes directly from the packed spectrum (no mg phase)
        float v[8]; int hiw[8];
#pragma unroll
        for (int q = 0; q < 8; ++q) {
            int m = (q << 6) | lane;
            int n = (1024 - m) & 1023;
            float2 Pk = spP[PAD16(m)];
            float2 Pn = spP[PAD16(n)];
            float rr, ii;
            if (c == 0) { rr = 0.5f * (Pk.x + Pn.x); ii = 0.5f * (Pk.y - Pn.y); }
            else        { rr = 0.5f * (Pk.y + Pn.y); ii = 0.5f * (Pn.x - Pk.x); }
            v[q] = rr * rr + ii * ii;
        }
        if (lane == 0) v[0] = -1.0f;   // exclude m=0; m=512 excluded by range
#pragma unroll
        for (int q = 0; q < 8; ++q) hiw[q] = __float_as_int(v[q]);

        int mx = hiw[0];
#pragma unroll
        for (int q = 1; q < 8; ++q) mx = max(mx, hiw[q]);
#pragma unroll
        for (int off = 1; off < 64; off <<= 1) mx = max(mx, __shfl_xor(mx, off));

        const int base = (mx >> 20) - 250;
        int idx[8];
#pragma unroll
        for (int q = 0; q < 8; ++q) {
            int t = (hiw[q] >> 20) - base;
            idx[q] = t < 0 ? 0 : t;
        }

        *reinterpret_cast<int4*>(&histc[lane << 2]) = int4{0, 0, 0, 0};
#pragma unroll
        for (int q = 0; q < 8; ++q) atomicAdd(&histc[idx[q]], 1);

        int4 cc = *reinterpret_cast<int4*>(&histc[lane << 2]);
        int s_local = cc.x + cc.y + cc.z + cc.w;

        int s = s_local;
#pragma unroll
        for (int off = 1; off < 64; off <<= 1) {
            int t = __shfl_down(s, off);
            if (lane + off < 64) s += t;
        }
        const int S_gt = s - s_local;
        const int A3 = S_gt;
        const int A2 = A3 + cc.w;
        const int A1 = A2 + cc.z;
        const int A0 = A1 + cc.y;

        int foundB = -1, foundR = 0;
        if (A0 < KSEL && A0 + cc.x >= KSEL) { foundB = (lane << 2) | 0; foundR = KSEL - A0; }
        if (A1 < KSEL && A1 + cc.y >= KSEL) { foundB = (lane << 2) | 1; foundR = KSEL - A1; }
        if (A2 < KSEL && A2 + cc.z >= KSEL) { foundB = (lane << 2) | 2; foundR = KSEL - A2; }
        if (A3 < KSEL && A3 + cc.w >= KSEL) { foundB = (lane << 2) | 3; foundR = KSEL - A3; }

        unsigned long long fm = __ballot(foundB >= 0);
        const int srcB = (int)(__ffsll((unsigned long long)fm) - 1);
        const int B = __shfl(foundB, srcB);
        const int r = __shfl(foundR, srcB);

        unsigned selmask = 0, candmask = 0;
#pragma unroll
        for (int q = 0; q < 8; ++q) {
            if (idx[q] > B) selmask |= (1u << q);
            else if (idx[q] == B) candmask |= (1u << q);
        }

        for (int it = 0; it < r; ++it) {
            float bv = -2.0f; int bq = -1;
#pragma unroll
            for (int q = 0; q < 8; ++q) {
                bool cand = ((candmask >> q) & 1u) != 0;
                if (cand && v[q] > bv) { bv = v[q]; bq = q; }
            }
            int bi = (bq < 0) ? 0x7FFFFFFF : ((bq << 6) | lane);
#pragma unroll
            for (int off = 1; off < 64; off <<= 1) {
                float ov = __shfl_xor(bv, off);
                int   oi = __shfl_xor(bi, off);
                if (ov > bv || (ov == bv && oi < bi)) { bv = ov; bi = oi; }
            }
            if (bi != 0x7FFFFFFF && lane == (bi & 63)) {
                unsigned bit = 1u << (bi >> 6);
                selmask  |= bit;
                candmask &= ~bit;
            }
        }

        // ---- fp64 refinement when the rank-32/33 fp32 gap is too small (reads x from global)
        {
            float vminS = 3.0e38f, vmaxU = -3.0e38f;
#pragma unroll
            for (int q = 0; q < 8; ++q) {
                if ((selmask >> q) & 1u) vminS = fminf(vminS, v[q]);
                else                     vmaxU = fmaxf(vmaxU, v[q]);
            }
#pragma unroll
            for (int off = 1; off < 64; off <<= 1) {
                vminS = fminf(vminS, __shfl_xor(vminS, off));
                vmaxU = fmaxf(vmaxU, __shfl_xor(vmaxU, off));
            }
            const float tau = RTAU * vminS;
            if (vminS - vmaxU < tau) {            // wave-uniform, rare
                const float lo = vmaxU - tau, hi = vminS + tau;
                unsigned candq = 0; int nAbove = 0;
#pragma unroll
                for (int q = 0; q < 8; ++q) {
                    bool inw = (v[q] >= lo) && (v[q] <= hi);
                    if (inw) candq |= (1u << q);
                    if (((selmask >> q) & 1u) && v[q] > hi) ++nAbove;
                }
#pragma unroll
                for (int off = 1; off < 64; off <<= 1) nAbove += __shfl_xor(nAbove, off);
                const int kneed = KSEL - nAbove;
                selmask &= ~candq;                 // drop window members; re-pick in fp64

                const float* xcol = x + ((size_t)(b << 10) << 8) + d0 + c;
                double sV = -1.0; int sSrc = 0; int cnum = 0;
                for (int q = 0; q < 8; ++q) {
                    unsigned long long bal = __ballot((candq >> q) & 1u);
                    while (bal) {
                        int srcl = (int)(__ffsll(bal) - 1);
                        bal &= bal - 1;
                        int m = (q << 6) | srcl;
                        double sr = 0.0, si = 0.0;
                        for (int u = 0; u < 16; ++u) {
                            int n = lane + (u << 6);
                            double xvd = (double)xcol[(size_t)n << 8];
                            int e = (m * n) & 1023;
                            sr = fma(xvd, gwr[e], sr);
                            si = fma(xvd, gwi[e], si);
                        }
#pragma unroll
                        for (int off = 1; off < 64; off <<= 1) {
                            sr += __shfl_xor(sr, off);
                            si += __shfl_xor(si, off);
                        }
                        if (lane == cnum) { sV = sr * sr + si * si; sSrc = (q << 6) | srcl; }
                        ++cnum;
                        if (cnum >= 64) break;
                    }
                    if (cnum >= 64) break;
                }
                for (int it = 0; it < kneed; ++it) {
                    double bv = sV; int bl = lane;
#pragma unroll
                    for (int off = 1; off < 64; off <<= 1) {
                        double ov = __shfl_xor(bv, off);
                        int    ol = __shfl_xor(bl, off);
                        if (ov > bv || (ov == bv && ol < bl)) { bv = ov; bl = ol; }
                    }
                    int wsrc = __shfl(sSrc, bl);
                    if (lane == (wsrc & 63)) selmask |= 1u << (wsrc >> 6);
                    if (lane == bl) sV = -2.0;
                }
            }
        }

        // ---- write selection bits (m only; mirror derived at read time)
#pragma unroll
        for (int q = 0; q < 8; ++q) {
            if ((selmask >> q) & 1u) {
                int m = (q << 6) | lane;           // 1..511
                atomicOr(&selw[(c << 4) | (m >> 5)], 1u << (m & 31));
            }
        }
    } else {
        // waves 2,3: Hermitian unpack spP -> X0[k], X1[k] (k = 0..511) in xunp
        const int t2 = tid - 128;                  // 0..127
#pragma unroll
        for (int j = 0; j < 4; ++j) {
            int k = t2 + (j << 7);                 // 0..511
            int n = (1024 - k) & 1023;
            float2 Pk = spP[PAD16(k)];
            float2 Pn = spP[PAD16(n)];
            xunp[k]       = float2{ 0.5f * (Pk.x + Pn.x), 0.5f * (Pk.y - Pn.y) };   // X0[k]
            xunp[512 + k] = float2{ 0.5f * (Pk.y + Pn.y), 0.5f * (Pn.x - Pk.x) };   // X1[k]
        }
    }
    __syncthreads();                                   // barrier 3

    // ---- build conj(Z) into spP (padded): Z[k] = s0*X0[k] + i*s1*X1[k]
#pragma unroll
    for (int jj = 0; jj < 4; ++jj) {
        int k = tid + (jj << 8);
        float2 z{ 0.0f, 0.0f };
        if (k != 0 && k != 512) {
            int fold = (k < 512) ? k : (1024 - k);
            float sgn = (k < 512) ? 1.0f : -1.0f;    // conj for mirrored half
            float2 X0 = xunp[fold];
            float2 X1 = xunp[512 + fold];
            X0.y *= sgn; X1.y *= sgn;
            bool s0 = (selw[fold >> 5]        >> (fold & 31)) & 1u;
            bool s1 = (selw[16 + (fold >> 5)] >> (fold & 31)) & 1u;
            float Zr = (s0 ? X0.x : 0.0f) - (s1 ? X1.y : 0.0f);
            float Zi = (s0 ? X0.y : 0.0f) + (s1 ? X1.x : 0.0f);
            z = float2{ Zr, -Zi };
        }
        spP[PAD16(k)] = z;
    }
    __syncthreads();                                   // barrier 4

    // ---- FFT 2 (inverse via conjugation): R[t] = DFT(conj(Z))[t] = conj(1024*y[t])
    fft1024<true>(spP, twF, lane, w, ar, ai);

    // ---- write y: out0 = Re(R)/1024, out1 = -Im(R)/1024; duplicate t<256 to t+1024
    {
        const float S = 1.0f / 1024.0f;
        float2* o2 = reinterpret_cast<float2*>(out + (size_t)b * OUT_T * DM + d0);
#pragma unroll
        for (int q = 0; q < 4; ++q) {
            int t = ((w << 2) | q) + (krev << 4);
            float2 o{ ar[q] * S, -ai[q] * S };
            o2[(size_t)t * 128] = o;
            if (t < PRED_LEN) o2[(size_t)(t + T_LEN) * 128] = o;
        }
    }
}

extern "C" void kernel_launch(void* const* d_in, const int* in_sizes, int n_in,
                              void* d_out, int out_size, void* d_ws, size_t ws_size,
                              hipStream_t stream) {
    const float* x = (const float*)d_in[0];
    float* out = (float*)d_out;

    char* w = (char*)d_ws;
    double* gwr = (double*)(w);
    double* gwi = (double*)(w + 1024 * sizeof(double));
    float2* gwF = (float2*)(w + 2048 * sizeof(double));

    hipLaunchKernelGGL(fl_twiddle_kernel, dim3(16), dim3(64), 0, stream, gwr, gwi, gwF);
    hipLaunchKernelGGL(fl_fused_kernel, dim3(1024), dim3(256), 0, stream,
                       x, gwr, gwi, gwF, out);
}

// Round 18
// 36.270 us; speedup vs baseline: 1.4570x; 1.1251x over previous
//
#include <hip/hip_runtime.h>
#include <math.h>

#define T_LEN 1024
#define PRED_LEN 256
#define OUT_T (T_LEN + PRED_LEN)
#define DM 256
#define KSEL 32
#define RTAU 1e-4f

#define PAD16(i) ((i) + ((i) >> 4))   // float2 arrays
#define C1024F 0.006135923151542565f  // 2*pi/1024

// W16[e] = exp(-2*pi*i*e/16), fp32
__device__ __constant__ float W16RF[16] = {
    1.0f,  0.92387953f,  0.70710678f,  0.38268343f, 0.0f, -0.38268343f, -0.70710678f, -0.92387953f,
   -1.0f, -0.92387953f, -0.70710678f, -0.38268343f, 0.0f,  0.38268343f,  0.70710678f,  0.92387953f };
__device__ __constant__ float W16IF[16] = {
    0.0f, -0.38268343f, -0.70710678f, -0.92387953f, -1.0f, -0.92387953f, -0.70710678f, -0.38268343f,
    0.0f,  0.38268343f,  0.70710678f,  0.92387953f,  1.0f,  0.92387953f,  0.70710678f,  0.38268343f };

// W16 in fp64 (refinement rotation steps): exp(-2*pi*i*e/16)
#define C1_ 0.92387953251128675613
#define C2_ 0.70710678118654752440
#define C3_ 0.38268343236508977173
__device__ __constant__ double W16R_[16] = {
    1.0,  C1_,  C2_,  C3_, 0.0, -C3_, -C2_, -C1_,
   -1.0, -C1_, -C2_, -C3_, 0.0,  C3_,  C2_,  C1_ };
__device__ __constant__ double W16I_[16] = {
    0.0, -C3_, -C2_, -C1_, -1.0, -C1_, -C2_, -C3_,
    0.0,  C3_,  C2_,  C1_,  1.0,  C1_,  C2_,  C3_ };

// ---- 1024-pt packed FFT core (16x64 four-step), LDS float2 twiddle table ----
// thread (w, lane): outputs X[k], k = ((w<<2)|q) + 16*rev6(lane)
template<bool PADDED>
__device__ __forceinline__ void fft1024(const float2* __restrict__ xin,
                                        const float2* __restrict__ twF,
                                        int lane, int w, float* ar, float* ai) {
    float Fr[4][4], Fi[4][4];
#pragma unroll
    for (int n1a = 0; n1a < 4; ++n1a) {
        int i0 = lane + 64 * (n1a + 0);
        int i1 = lane + 64 * (n1a + 4);
        int i2 = lane + 64 * (n1a + 8);
        int i3 = lane + 64 * (n1a + 12);
        float2 a  = xin[PADDED ? PAD16(i0) : i0];
        float2 bb = xin[PADDED ? PAD16(i1) : i1];
        float2 cV = xin[PADDED ? PAD16(i2) : i2];
        float2 d  = xin[PADDED ? PAD16(i3) : i3];
        float t0r = a.x + cV.x, t0i = a.y + cV.y;
        float t1r = a.x - cV.x, t1i = a.y - cV.y;
        float t2r = bb.x + d.x, t2i = bb.y + d.y;
        float t3r = bb.x - d.x, t3i = bb.y - d.y;
        Fr[n1a][0] = t0r + t2r;  Fi[n1a][0] = t0i + t2i;
        Fr[n1a][2] = t0r - t2r;  Fi[n1a][2] = t0i - t2i;
        Fr[n1a][1] = t1r + t3i;  Fi[n1a][1] = t1i - t3r;   // t1 - i*t3
        Fr[n1a][3] = t1r - t3i;  Fi[n1a][3] = t1i + t3r;   // t1 + i*t3
    }
#pragma unroll
    for (int q = 0; q < 4; ++q) {
        const int k1 = (w << 2) | q;
        float cr = Fr[0][q], ci = Fi[0][q];
#pragma unroll
        for (int n1a = 1; n1a < 4; ++n1a) {
            int e = (n1a * k1) & 15;
            float wr = W16RF[e], wi = W16IF[e];
            cr += Fr[n1a][q] * wr - Fi[n1a][q] * wi;
            ci += Fr[n1a][q] * wi + Fi[n1a][q] * wr;
        }
        float2 tw = twF[PAD16((lane * k1) & 1023)];
        ar[q] = cr * tw.x - ci * tw.y;
        ai[q] = cr * tw.y + ci * tw.x;
    }
#pragma unroll
    for (int s = 0; s < 6; ++s) {
        const int half = 32 >> s;
        const int e = (lane & (half - 1)) << s;          // < 32
        float2 tw = twF[PAD16(e << 4)];                  // W64^e = W1024^(16e)
        const bool up = (lane & half) != 0;
#pragma unroll
        for (int q = 0; q < 4; ++q) {
            float orr = __shfl_xor(ar[q], half);
            float oii = __shfl_xor(ai[q], half);
            float sr = ar[q] + orr, si = ai[q] + oii;
            float dr = orr - ar[q], di = oii - ai[q];
            ar[q] = up ? (dr * tw.x - di * tw.y) : sr;
            ai[q] = up ? (dr * tw.y + di * tw.x) : si;
        }
    }
}

// ---------------- Single fused kernel: fp32 FFT + overlapped {top-32 | unpack} + fp64 refine + inverse-FFT ----
// grid = 1024 blocks (one column-pair each), block = 256 threads = 4 waves.
__global__ void __launch_bounds__(256, 4)
fl_fused_kernel(const float* __restrict__ x, float* __restrict__ out) {
    __shared__ float2 twF[PAD16(1023) + 1];   // fp32 twiddle table (computed in-block)
    __shared__ float2 spP[PAD16(1023) + 1];   // packed spectrum -> later conj(Z)
    __shared__ char smemU[8192];              // union: xsh (FFT1 in) | xunp {X0[512], X1[512]}
    __shared__ int hist[512];                 // 256 bins per column
    __shared__ unsigned selw[32];             // selection bitsets: [c][m>>5], m in 0..511
    float2* xsh  = (float2*)smemU;
    float2* xunp = (float2*)smemU;            // X0 at [0..511], X1 at [512..1023]

    const int tid  = threadIdx.x;
    const int lane = tid & 63;
    const int w    = tid >> 6;

    const int bid = blockIdx.x;
    const int sp  = ((bid & 7) << 7) | (bid >> 3);   // XCD-chunked, bijective over 1024
    const int b   = sp >> 7;
    const int d0  = (sp & 127) << 1;

    // compute fp32 twiddles in-block (no global table) and stage the column-pair
    for (int j = 0; j < 4; ++j) {
        int e = tid + (j << 8);
        float sn, cs;
        __sincosf((float)e * C1024F, &sn, &cs);
        twF[PAD16(e)] = float2{ cs, -sn };
        xsh[e] = *reinterpret_cast<const float2*>(&x[(((size_t)(b << 10) + e) << 8) + d0]);
    }
    if (tid < 32) selw[tid] = 0u;
    __syncthreads();                                   // barrier 1

    // ---- FFT 1: forward transform of packed pair
    float ar[4], ai[4];
    fft1024<false>(xsh, twF, lane, w, ar, ai);

    const int krev = (int)(__brev((unsigned)lane) >> 26);  // rev6(lane)
#pragma unroll
    for (int q = 0; q < 4; ++q) {
        int k = ((w << 2) | q) + (krev << 4);
        spP[PAD16(k)] = float2{ ar[q], ai[q] };
    }
    __syncthreads();                                   // barrier 2

    // ---- divergent phase: waves 0,1 do top-k; waves 2,3 unpack X0/X1 into xunp
    if (tid < 128) {
        const int c = tid >> 6;
        int* histc = hist + (c << 8);

        // magnitudes directly from the packed spectrum
        float v[8]; int hiw[8];
#pragma unroll
        for (int q = 0; q < 8; ++q) {
            int m = (q << 6) | lane;
            int n = (1024 - m) & 1023;
            float2 Pk = spP[PAD16(m)];
            float2 Pn = spP[PAD16(n)];
            float rr, ii;
            if (c == 0) { rr = 0.5f * (Pk.x + Pn.x); ii = 0.5f * (Pk.y - Pn.y); }
            else        { rr = 0.5f * (Pk.y + Pn.y); ii = 0.5f * (Pn.x - Pk.x); }
            v[q] = rr * rr + ii * ii;
        }
        if (lane == 0) v[0] = -1.0f;   // exclude m=0; m=512 excluded by range
#pragma unroll
        for (int q = 0; q < 8; ++q) hiw[q] = __float_as_int(v[q]);

        int mx = hiw[0];
#pragma unroll
        for (int q = 1; q < 8; ++q) mx = max(mx, hiw[q]);
#pragma unroll
        for (int off = 1; off < 64; off <<= 1) mx = max(mx, __shfl_xor(mx, off));

        const int base = (mx >> 20) - 250;
        int idx[8];
#pragma unroll
        for (int q = 0; q < 8; ++q) {
            int t = (hiw[q] >> 20) - base;
            idx[q] = t < 0 ? 0 : t;
        }

        *reinterpret_cast<int4*>(&histc[lane << 2]) = int4{0, 0, 0, 0};
#pragma unroll
        for (int q = 0; q < 8; ++q) atomicAdd(&histc[idx[q]], 1);

        int4 cc = *reinterpret_cast<int4*>(&histc[lane << 2]);
        int s_local = cc.x + cc.y + cc.z + cc.w;

        int s = s_local;
#pragma unroll
        for (int off = 1; off < 64; off <<= 1) {
            int t = __shfl_down(s, off);
            if (lane + off < 64) s += t;
        }
        const int S_gt = s - s_local;
        const int A3 = S_gt;
        const int A2 = A3 + cc.w;
        const int A1 = A2 + cc.z;
        const int A0 = A1 + cc.y;

        int foundB = -1, foundR = 0;
        if (A0 < KSEL && A0 + cc.x >= KSEL) { foundB = (lane << 2) | 0; foundR = KSEL - A0; }
        if (A1 < KSEL && A1 + cc.y >= KSEL) { foundB = (lane << 2) | 1; foundR = KSEL - A1; }
        if (A2 < KSEL && A2 + cc.z >= KSEL) { foundB = (lane << 2) | 2; foundR = KSEL - A2; }
        if (A3 < KSEL && A3 + cc.w >= KSEL) { foundB = (lane << 2) | 3; foundR = KSEL - A3; }

        unsigned long long fm = __ballot(foundB >= 0);
        const int srcB = (int)(__ffsll((unsigned long long)fm) - 1);
        const int B = __shfl(foundB, srcB);
        const int r = __shfl(foundR, srcB);

        unsigned selmask = 0, candmask = 0;
#pragma unroll
        for (int q = 0; q < 8; ++q) {
            if (idx[q] > B) selmask |= (1u << q);
            else if (idx[q] == B) candmask |= (1u << q);
        }

        for (int it = 0; it < r; ++it) {
            float bv = -2.0f; int bq = -1;
#pragma unroll
            for (int q = 0; q < 8; ++q) {
                bool cand = ((candmask >> q) & 1u) != 0;
                if (cand && v[q] > bv) { bv = v[q]; bq = q; }
            }
            int bi = (bq < 0) ? 0x7FFFFFFF : ((bq << 6) | lane);
#pragma unroll
            for (int off = 1; off < 64; off <<= 1) {
                float ov = __shfl_xor(bv, off);
                int   oi = __shfl_xor(bi, off);
                if (ov > bv || (ov == bv && oi < bi)) { bv = ov; bi = oi; }
            }
            if (bi != 0x7FFFFFFF && lane == (bi & 63)) {
                unsigned bit = 1u << (bi >> 6);
                selmask  |= bit;
                candmask &= ~bit;
            }
        }

        // ---- fp64 refinement when the rank-32/33 fp32 gap is too small.
        // Twiddles via one fp64 sincos seed + exact W16 rotation recurrence (no table).
        {
            float vminS = 3.0e38f, vmaxU = -3.0e38f;
#pragma unroll
            for (int q = 0; q < 8; ++q) {
                if ((selmask >> q) & 1u) vminS = fminf(vminS, v[q]);
                else                     vmaxU = fmaxf(vmaxU, v[q]);
            }
#pragma unroll
            for (int off = 1; off < 64; off <<= 1) {
                vminS = fminf(vminS, __shfl_xor(vminS, off));
                vmaxU = fmaxf(vmaxU, __shfl_xor(vmaxU, off));
            }
            const float tau = RTAU * vminS;
            if (vminS - vmaxU < tau) {            // wave-uniform, rare
                const float lo = vmaxU - tau, hi = vminS + tau;
                unsigned candq = 0; int nAbove = 0;
#pragma unroll
                for (int q = 0; q < 8; ++q) {
                    bool inw = (v[q] >= lo) && (v[q] <= hi);
                    if (inw) candq |= (1u << q);
                    if (((selmask >> q) & 1u) && v[q] > hi) ++nAbove;
                }
#pragma unroll
                for (int off = 1; off < 64; off <<= 1) nAbove += __shfl_xor(nAbove, off);
                const int kneed = KSEL - nAbove;
                selmask &= ~candq;                 // drop window members; re-pick in fp64

                const float* xcol = x + ((size_t)(b << 10) << 8) + d0 + c;
                double sV = -1.0; int sSrc = 0; int cnum = 0;
                for (int q = 0; q < 8; ++q) {
                    unsigned long long bal = __ballot((candq >> q) & 1u);
                    while (bal) {
                        int srcl = (int)(__ffsll(bal) - 1);
                        bal &= bal - 1;
                        int m = (q << 6) | srcl;
                        // lane-local twiddle chain: e_u = m*lane + 64*m*u (mod 1024)
                        double th0 = (double)((m * lane) & 1023)
                                   * (-6.283185307179586476925286766559 / 1024.0);
                        double wr, wi;
                        { double s0, c0; sincos(th0, &s0, &c0); wr = c0; wi = s0; }
                        const double stR = W16R_[m & 15], stI = W16I_[m & 15];
                        double sr = 0.0, si = 0.0;
#pragma unroll
                        for (int u = 0; u < 16; ++u) {
                            int n = lane + (u << 6);
                            double xvd = (double)xcol[(size_t)n << 8];
                            sr = fma(xvd, wr, sr);
                            si = fma(xvd, wi, si);
                            double nwr = wr * stR - wi * stI;
                            double nwi = wr * stI + wi * stR;
                            wr = nwr; wi = nwi;
                        }
#pragma unroll
                        for (int off = 1; off < 64; off <<= 1) {
                            sr += __shfl_xor(sr, off);
                            si += __shfl_xor(si, off);
                        }
                        if (lane == cnum) { sV = sr * sr + si * si; sSrc = (q << 6) | srcl; }
                        ++cnum;
                        if (cnum >= 64) break;
                    }
                    if (cnum >= 64) break;
                }
                for (int it = 0; it < kneed; ++it) {
                    double bv = sV; int bl = lane;
#pragma unroll
                    for (int off = 1; off < 64; off <<= 1) {
                        double ov = __shfl_xor(bv, off);
                        int    ol = __shfl_xor(bl, off);
                        if (ov > bv || (ov == bv && ol < bl)) { bv = ov; bl = ol; }
                    }
                    int wsrc = __shfl(sSrc, bl);
                    if (lane == (wsrc & 63)) selmask |= 1u << (wsrc >> 6);
                    if (lane == bl) sV = -2.0;
                }
            }
        }

        // ---- write selection bits (m only; mirror derived at read time)
#pragma unroll
        for (int q = 0; q < 8; ++q) {
            if ((selmask >> q) & 1u) {
                int m = (q << 6) | lane;           // 1..511
                atomicOr(&selw[(c << 4) | (m >> 5)], 1u << (m & 31));
            }
        }
    } else {
        // waves 2,3: Hermitian unpack spP -> X0[k], X1[k] (k = 0..511) in xunp
        const int t2 = tid - 128;                  // 0..127
#pragma unroll
        for (int j = 0; j < 4; ++j) {
            int k = t2 + (j << 7);                 // 0..511
            int n = (1024 - k) & 1023;
            float2 Pk = spP[PAD16(k)];
            float2 Pn = spP[PAD16(n)];
            xunp[k]       = float2{ 0.5f * (Pk.x + Pn.x), 0.5f * (Pk.y - Pn.y) };   // X0[k]
            xunp[512 + k] = float2{ 0.5f * (Pk.y + Pn.y), 0.5f * (Pn.x - Pk.x) };   // X1[k]
        }
    }
    __syncthreads();                                   // barrier 3

    // ---- build conj(Z) into spP (padded): Z[k] = s0*X0[k] + i*s1*X1[k]
#pragma unroll
    for (int jj = 0; jj < 4; ++jj) {
        int k = tid + (jj << 8);
        float2 z{ 0.0f, 0.0f };
        if (k != 0 && k != 512) {
            int fold = (k < 512) ? k : (1024 - k);
            float sgn = (k < 512) ? 1.0f : -1.0f;    // conj for mirrored half
            float2 X0 = xunp[fold];
            float2 X1 = xunp[512 + fold];
            X0.y *= sgn; X1.y *= sgn;
            bool s0 = (selw[fold >> 5]        >> (fold & 31)) & 1u;
            bool s1 = (selw[16 + (fold >> 5)] >> (fold & 31)) & 1u;
            float Zr = (s0 ? X0.x : 0.0f) - (s1 ? X1.y : 0.0f);
            float Zi = (s0 ? X0.y : 0.0f) + (s1 ? X1.x : 0.0f);
            z = float2{ Zr, -Zi };
        }
        spP[PAD16(k)] = z;
    }
    __syncthreads();                                   // barrier 4

    // ---- FFT 2 (inverse via conjugation): R[t] = DFT(conj(Z))[t] = conj(1024*y[t])
    fft1024<true>(spP, twF, lane, w, ar, ai);

    // ---- write y: out0 = Re(R)/1024, out1 = -Im(R)/1024; duplicate t<256 to t+1024
    {
        const float S = 1.0f / 1024.0f;
        float2* o2 = reinterpret_cast<float2*>(out + (size_t)b * OUT_T * DM + d0);
#pragma unroll
        for (int q = 0; q < 4; ++q) {
            int t = ((w << 2) | q) + (krev << 4);
            float2 o{ ar[q] * S, -ai[q] * S };
            o2[(size_t)t * 128] = o;
            if (t < PRED_LEN) o2[(size_t)(t + T_LEN) * 128] = o;
        }
    }
}

extern "C" void kernel_launch(void* const* d_in, const int* in_sizes, int n_in,
                              void* d_out, int out_size, void* d_ws, size_t ws_size,
                              hipStream_t stream) {
    const float* x = (const float*)d_in[0];
    float* out = (float*)d_out;
    hipLaunchKernelGGL(fl_fused_kernel, dim3(1024), dim3(256), 0, stream, x, out);
}

// Round 19
// 35.363 us; speedup vs baseline: 1.4944x; 1.0256x over previous
//
#include <hip/hip_runtime.h>
#include <math.h>

#define T_LEN 1024
#define PRED_LEN 256
#define OUT_T (T_LEN + PRED_LEN)
#define DM 256
#define KSEL 32
#define RTAU 1e-4f

#define PAD16(i) ((i) + ((i) >> 4))   // float2 arrays
#define C1024F 0.006135923151542565f  // 2*pi/1024

// W16[e] = exp(-2*pi*i*e/16), fp32
__device__ __constant__ float W16RF[16] = {
    1.0f,  0.92387953f,  0.70710678f,  0.38268343f, 0.0f, -0.38268343f, -0.70710678f, -0.92387953f,
   -1.0f, -0.92387953f, -0.70710678f, -0.38268343f, 0.0f,  0.38268343f,  0.70710678f,  0.92387953f };
__device__ __constant__ float W16IF[16] = {
    0.0f, -0.38268343f, -0.70710678f, -0.92387953f, -1.0f, -0.92387953f, -0.70710678f, -0.38268343f,
    0.0f,  0.38268343f,  0.70710678f,  0.92387953f,  1.0f,  0.92387953f,  0.70710678f,  0.38268343f };

// W16 in fp64 (refinement rotation steps): exp(-2*pi*i*e/16)
#define C1_ 0.92387953251128675613
#define C2_ 0.70710678118654752440
#define C3_ 0.38268343236508977173
__device__ __constant__ double W16R_[16] = {
    1.0,  C1_,  C2_,  C3_, 0.0, -C3_, -C2_, -C1_,
   -1.0, -C1_, -C2_, -C3_, 0.0,  C3_,  C2_,  C1_ };
__device__ __constant__ double W16I_[16] = {
    0.0, -C3_, -C2_, -C1_, -1.0, -C1_, -C2_, -C3_,
    0.0,  C3_,  C2_,  C1_,  1.0,  C1_,  C2_,  C3_ };

// ---- masked-spectrum value for FFT2 (computed on the fly; replaces the Zc-build phase)
__device__ __forceinline__ float2 zval(const float2* __restrict__ xunp,
                                       const unsigned* __restrict__ selw, int k) {
    if (k == 0 || k == 512) return float2{ 0.f, 0.f };
    const int  fold = (k < 512) ? k : (1024 - k);
    const float sgn = (k < 512) ? 1.0f : -1.0f;
    float2 X0 = xunp[fold];
    float2 X1 = xunp[512 + fold];
    const bool s0 = (selw[fold >> 5]        >> (fold & 31)) & 1u;
    const bool s1 = (selw[16 + (fold >> 5)] >> (fold & 31)) & 1u;
    float x0i = sgn * X0.y;
    float x1i = sgn * X1.y;
    float Zr = (s0 ? X0.x : 0.f) - (s1 ? x1i : 0.f);
    float Zi = (s0 ? x0i : 0.f) + (s1 ? X1.x : 0.f);
    return float2{ Zr, -Zi };
}

// ---- 1024-pt packed FFT core (16x64 four-step), LDS float2 twiddle table ----
// thread (w, lane): outputs X[k], k = ((w<<2)|q) + 16*rev6(lane)
__device__ __forceinline__ void fft1024(const float2* __restrict__ xin,
                                        const float2* __restrict__ twF,
                                        int lane, int w, float* ar, float* ai) {
    float Fr[4][4], Fi[4][4];
#pragma unroll
    for (int n1a = 0; n1a < 4; ++n1a) {
        float2 a  = xin[lane + 64 * (n1a + 0)];
        float2 bb = xin[lane + 64 * (n1a + 4)];
        float2 cV = xin[lane + 64 * (n1a + 8)];
        float2 d  = xin[lane + 64 * (n1a + 12)];
        float t0r = a.x + cV.x, t0i = a.y + cV.y;
        float t1r = a.x - cV.x, t1i = a.y - cV.y;
        float t2r = bb.x + d.x, t2i = bb.y + d.y;
        float t3r = bb.x - d.x, t3i = bb.y - d.y;
        Fr[n1a][0] = t0r + t2r;  Fi[n1a][0] = t0i + t2i;
        Fr[n1a][2] = t0r - t2r;  Fi[n1a][2] = t0i - t2i;
        Fr[n1a][1] = t1r + t3i;  Fi[n1a][1] = t1i - t3r;   // t1 - i*t3
        Fr[n1a][3] = t1r - t3i;  Fi[n1a][3] = t1i + t3r;   // t1 + i*t3
    }
#pragma unroll
    for (int q = 0; q < 4; ++q) {
        const int k1 = (w << 2) | q;
        float cr = Fr[0][q], ci = Fi[0][q];
#pragma unroll
        for (int n1a = 1; n1a < 4; ++n1a) {
            int e = (n1a * k1) & 15;
            float wr = W16RF[e], wi = W16IF[e];
            cr += Fr[n1a][q] * wr - Fi[n1a][q] * wi;
            ci += Fr[n1a][q] * wi + Fi[n1a][q] * wr;
        }
        float2 tw = twF[PAD16((lane * k1) & 1023)];
        ar[q] = cr * tw.x - ci * tw.y;
        ai[q] = cr * tw.y + ci * tw.x;
    }
#pragma unroll
    for (int s = 0; s < 6; ++s) {
        const int half = 32 >> s;
        const int e = (lane & (half - 1)) << s;          // < 32
        float2 tw = twF[PAD16(e << 4)];                  // W64^e = W1024^(16e)
        const bool up = (lane & half) != 0;
#pragma unroll
        for (int q = 0; q < 4; ++q) {
            float orr = __shfl_xor(ar[q], half);
            float oii = __shfl_xor(ai[q], half);
            float sr = ar[q] + orr, si = ai[q] + oii;
            float dr = orr - ar[q], di = oii - ai[q];
            ar[q] = up ? (dr * tw.x - di * tw.y) : sr;
            ai[q] = up ? (dr * tw.y + di * tw.x) : si;
        }
    }
}

// ---- same core, but input generated via zval (masked spectrum) ----
__device__ __forceinline__ void fft1024_z(const float2* __restrict__ xunp,
                                          const unsigned* __restrict__ selw,
                                          const float2* __restrict__ twF,
                                          int lane, int w, float* ar, float* ai) {
    float Fr[4][4], Fi[4][4];
#pragma unroll
    for (int n1a = 0; n1a < 4; ++n1a) {
        float2 a  = zval(xunp, selw, lane + 64 * (n1a + 0));
        float2 bb = zval(xunp, selw, lane + 64 * (n1a + 4));
        float2 cV = zval(xunp, selw, lane + 64 * (n1a + 8));
        float2 d  = zval(xunp, selw, lane + 64 * (n1a + 12));
        float t0r = a.x + cV.x, t0i = a.y + cV.y;
        float t1r = a.x - cV.x, t1i = a.y - cV.y;
        float t2r = bb.x + d.x, t2i = bb.y + d.y;
        float t3r = bb.x - d.x, t3i = bb.y - d.y;
        Fr[n1a][0] = t0r + t2r;  Fi[n1a][0] = t0i + t2i;
        Fr[n1a][2] = t0r - t2r;  Fi[n1a][2] = t0i - t2i;
        Fr[n1a][1] = t1r + t3i;  Fi[n1a][1] = t1i - t3r;
        Fr[n1a][3] = t1r - t3i;  Fi[n1a][3] = t1i + t3r;
    }
#pragma unroll
    for (int q = 0; q < 4; ++q) {
        const int k1 = (w << 2) | q;
        float cr = Fr[0][q], ci = Fi[0][q];
#pragma unroll
        for (int n1a = 1; n1a < 4; ++n1a) {
            int e = (n1a * k1) & 15;
            float wr = W16RF[e], wi = W16IF[e];
            cr += Fr[n1a][q] * wr - Fi[n1a][q] * wi;
            ci += Fr[n1a][q] * wi + Fi[n1a][q] * wr;
        }
        float2 tw = twF[PAD16((lane * k1) & 1023)];
        ar[q] = cr * tw.x - ci * tw.y;
        ai[q] = cr * tw.y + ci * tw.x;
    }
#pragma unroll
    for (int s = 0; s < 6; ++s) {
        const int half = 32 >> s;
        const int e = (lane & (half - 1)) << s;
        float2 tw = twF[PAD16(e << 4)];
        const bool up = (lane & half) != 0;
#pragma unroll
        for (int q = 0; q < 4; ++q) {
            float orr = __shfl_xor(ar[q], half);
            float oii = __shfl_xor(ai[q], half);
            float sr = ar[q] + orr, si = ai[q] + oii;
            float dr = orr - ar[q], di = oii - ai[q];
            ar[q] = up ? (dr * tw.x - di * tw.y) : sr;
            ai[q] = up ? (dr * tw.y + di * tw.x) : si;
        }
    }
}

// ---------------- Single fused kernel ----------------
// grid = 1024 blocks (one column-pair each), block = 256 threads = 4 waves.
__global__ void __launch_bounds__(256, 4)
fl_fused_kernel(const float* __restrict__ x, float* __restrict__ out) {
    __shared__ float2 twF[PAD16(1023) + 1];   // fp32 twiddle table (computed in-block)
    __shared__ float2 spP[PAD16(1023) + 1];   // packed spectrum
    __shared__ char smemU[8192];              // union: xsh (FFT1 in) | xunp {X0[512], X1[512]}
    __shared__ int hist[512];                 // 256 bins per column
    __shared__ unsigned selw[32];             // selection bitsets: [c][m>>5], m in 0..511
    float2* xsh  = (float2*)smemU;
    float2* xunp = (float2*)smemU;            // X0 at [0..511], X1 at [512..1023]

    const int tid  = threadIdx.x;
    const int lane = tid & 63;
    const int w    = tid >> 6;

    const int bid = blockIdx.x;
    const int sp  = ((bid & 7) << 7) | (bid >> 3);   // XCD-chunked, bijective over 1024
    const int b   = sp >> 7;
    const int d0  = (sp & 127) << 1;

    // compute fp32 twiddles in-block and stage the column-pair
    for (int j = 0; j < 4; ++j) {
        int e = tid + (j << 8);
        float sn, cs;
        __sincosf((float)e * C1024F, &sn, &cs);
        twF[PAD16(e)] = float2{ cs, -sn };
        xsh[e] = *reinterpret_cast<const float2*>(&x[(((size_t)(b << 10) + e) << 8) + d0]);
    }
    if (tid < 32) selw[tid] = 0u;
    __syncthreads();                                   // barrier 1

    // ---- FFT 1: forward transform of packed pair
    float ar[4], ai[4];
    fft1024(xsh, twF, lane, w, ar, ai);

    const int krev = (int)(__brev((unsigned)lane) >> 26);  // rev6(lane)
#pragma unroll
    for (int q = 0; q < 4; ++q) {
        int k = ((w << 2) | q) + (krev << 4);
        spP[PAD16(k)] = float2{ ar[q], ai[q] };
    }
    __syncthreads();                                   // barrier 2

    // ---- divergent phase: waves 0,1 do top-k; waves 2,3 unpack X0/X1 into xunp
    if (tid < 128) {
        const int c = tid >> 6;
        int* histc = hist + (c << 8);

        // magnitudes directly from the packed spectrum
        float v[8]; int hiw[8];
#pragma unroll
        for (int q = 0; q < 8; ++q) {
            int m = (q << 6) | lane;
            int n = (1024 - m) & 1023;
            float2 Pk = spP[PAD16(m)];
            float2 Pn = spP[PAD16(n)];
            float rr, ii;
            if (c == 0) { rr = 0.5f * (Pk.x + Pn.x); ii = 0.5f * (Pk.y - Pn.y); }
            else        { rr = 0.5f * (Pk.y + Pn.y); ii = 0.5f * (Pn.x - Pk.x); }
            v[q] = rr * rr + ii * ii;
        }
        if (lane == 0) v[0] = -1.0f;   // exclude m=0; m=512 excluded by range
#pragma unroll
        for (int q = 0; q < 8; ++q) hiw[q] = __float_as_int(v[q]);

        int mx = hiw[0];
#pragma unroll
        for (int q = 1; q < 8; ++q) mx = max(mx, hiw[q]);
#pragma unroll
        for (int off = 1; off < 64; off <<= 1) mx = max(mx, __shfl_xor(mx, off));

        const int base = (mx >> 20) - 250;
        int idx[8];
#pragma unroll
        for (int q = 0; q < 8; ++q) {
            int t = (hiw[q] >> 20) - base;
            idx[q] = t < 0 ? 0 : t;
        }

        *reinterpret_cast<int4*>(&histc[lane << 2]) = int4{0, 0, 0, 0};
#pragma unroll
        for (int q = 0; q < 8; ++q) atomicAdd(&histc[idx[q]], 1);

        int4 cc = *reinterpret_cast<int4*>(&histc[lane << 2]);
        int s_local = cc.x + cc.y + cc.z + cc.w;

        int s = s_local;
#pragma unroll
        for (int off = 1; off < 64; off <<= 1) {
            int t = __shfl_down(s, off);
            if (lane + off < 64) s += t;
        }
        const int S_gt = s - s_local;
        const int A3 = S_gt;
        const int A2 = A3 + cc.w;
        const int A1 = A2 + cc.z;
        const int A0 = A1 + cc.y;

        int foundB = -1, foundR = 0;
        if (A0 < KSEL && A0 + cc.x >= KSEL) { foundB = (lane << 2) | 0; foundR = KSEL - A0; }
        if (A1 < KSEL && A1 + cc.y >= KSEL) { foundB = (lane << 2) | 1; foundR = KSEL - A1; }
        if (A2 < KSEL && A2 + cc.z >= KSEL) { foundB = (lane << 2) | 2; foundR = KSEL - A2; }
        if (A3 < KSEL && A3 + cc.w >= KSEL) { foundB = (lane << 2) | 3; foundR = KSEL - A3; }

        unsigned long long fm = __ballot(foundB >= 0);
        const int srcB = (int)(__ffsll((unsigned long long)fm) - 1);
        int B = __shfl(foundB, srcB);
        int r = __shfl(foundR, srcB);

        unsigned selmask = 0, candmask = 0;
#pragma unroll
        for (int q = 0; q < 8; ++q) {
            if (idx[q] > B) selmask |= (1u << q);
            else if (idx[q] == B) candmask |= (1u << q);
        }

        // ---- second-level histogram: orders bin-B members by mantissa bits 12..19
        // (valid when B>0: all bin-B members share bits >=20). Cuts argmax rounds.
        if (r > 0 && B > 0) {
            *reinterpret_cast<int4*>(&histc[lane << 2]) = int4{0, 0, 0, 0};
            int idx2[8];
#pragma unroll
            for (int q = 0; q < 8; ++q) {
                idx2[q] = (hiw[q] >> 12) & 255;
                if ((candmask >> q) & 1u) atomicAdd(&histc[idx2[q]], 1);
            }
            int4 c2 = *reinterpret_cast<int4*>(&histc[lane << 2]);
            int s2l = c2.x + c2.y + c2.z + c2.w;
            int ss = s2l;
#pragma unroll
            for (int off = 1; off < 64; off <<= 1) {
                int t = __shfl_down(ss, off);
                if (lane + off < 64) ss += t;
            }
            const int G3 = ss - s2l;
            const int G2 = G3 + c2.w;
            const int G1 = G2 + c2.z;
            const int G0 = G1 + c2.y;
            int fB2 = -1, fR2 = 0;
            if (G0 < r && G0 + c2.x >= r) { fB2 = (lane << 2) | 0; fR2 = r - G0; }
            if (G1 < r && G1 + c2.y >= r) { fB2 = (lane << 2) | 1; fR2 = r - G1; }
            if (G2 < r && G2 + c2.z >= r) { fB2 = (lane << 2) | 2; fR2 = r - G2; }
            if (G3 < r && G3 + c2.w >= r) { fB2 = (lane << 2) | 3; fR2 = r - G3; }
            unsigned long long fm2 = __ballot(fB2 >= 0);
            const int src2 = (int)(__ffsll((unsigned long long)fm2) - 1);
            const int Bb = __shfl(fB2, src2);
            const int rr = __shfl(fR2, src2);
            unsigned newcand = 0;
#pragma unroll
            for (int q = 0; q < 8; ++q) {
                if ((candmask >> q) & 1u) {
                    if (idx2[q] > Bb) selmask |= (1u << q);
                    else if (idx2[q] == Bb) newcand |= (1u << q);
                }
            }
            candmask = newcand;
            r = rr;
        }

        for (int it = 0; it < r; ++it) {
            float bv = -2.0f; int bq = -1;
#pragma unroll
            for (int q = 0; q < 8; ++q) {
                bool cand = ((candmask >> q) & 1u) != 0;
                if (cand && v[q] > bv) { bv = v[q]; bq = q; }
            }
            int bi = (bq < 0) ? 0x7FFFFFFF : ((bq << 6) | lane);
#pragma unroll
            for (int off = 1; off < 64; off <<= 1) {
                float ov = __shfl_xor(bv, off);
                int   oi = __shfl_xor(bi, off);
                if (ov > bv || (ov == bv && oi < bi)) { bv = ov; bi = oi; }
            }
            if (bi != 0x7FFFFFFF && lane == (bi & 63)) {
                unsigned bit = 1u << (bi >> 6);
                selmask  |= bit;
                candmask &= ~bit;
            }
        }

        // ---- fp64 refinement when the rank-32/33 fp32 gap is too small.
        {
            float vminS = 3.0e38f, vmaxU = -3.0e38f;
#pragma unroll
            for (int q = 0; q < 8; ++q) {
                if ((selmask >> q) & 1u) vminS = fminf(vminS, v[q]);
                else                     vmaxU = fmaxf(vmaxU, v[q]);
            }
#pragma unroll
            for (int off = 1; off < 64; off <<= 1) {
                vminS = fminf(vminS, __shfl_xor(vminS, off));
                vmaxU = fmaxf(vmaxU, __shfl_xor(vmaxU, off));
            }
            const float tau = RTAU * vminS;
            if (vminS - vmaxU < tau) {            // wave-uniform, rare
                const float lo = vmaxU - tau, hi = vminS + tau;
                unsigned candq = 0; int nAbove = 0;
#pragma unroll
                for (int q = 0; q < 8; ++q) {
                    bool inw = (v[q] >= lo) && (v[q] <= hi);
                    if (inw) candq |= (1u << q);
                    if (((selmask >> q) & 1u) && v[q] > hi) ++nAbove;
                }
#pragma unroll
                for (int off = 1; off < 64; off <<= 1) nAbove += __shfl_xor(nAbove, off);
                const int kneed = KSEL - nAbove;
                selmask &= ~candq;

                const float* xcol = x + ((size_t)(b << 10) << 8) + d0 + c;
                double sV = -1.0; int sSrc = 0; int cnum = 0;
                for (int q = 0; q < 8; ++q) {
                    unsigned long long bal = __ballot((candq >> q) & 1u);
                    while (bal) {
                        int srcl = (int)(__ffsll(bal) - 1);
                        bal &= bal - 1;
                        int m = (q << 6) | srcl;
                        double th0 = (double)((m * lane) & 1023)
                                   * (-6.283185307179586476925286766559 / 1024.0);
                        double wr, wi;
                        { double s0, c0; sincos(th0, &s0, &c0); wr = c0; wi = s0; }
                        const double stR = W16R_[m & 15], stI = W16I_[m & 15];
                        double sr = 0.0, si = 0.0;
#pragma unroll
                        for (int u = 0; u < 16; ++u) {
                            int n = lane + (u << 6);
                            double xvd = (double)xcol[(size_t)n << 8];
                            sr = fma(xvd, wr, sr);
                            si = fma(xvd, wi, si);
                            double nwr = wr * stR - wi * stI;
                            double nwi = wr * stI + wi * stR;
                            wr = nwr; wi = nwi;
                        }
#pragma unroll
                        for (int off = 1; off < 64; off <<= 1) {
                            sr += __shfl_xor(sr, off);
                            si += __shfl_xor(si, off);
                        }
                        if (lane == cnum) { sV = sr * sr + si * si; sSrc = (q << 6) | srcl; }
                        ++cnum;
                        if (cnum >= 64) break;
                    }
                    if (cnum >= 64) break;
                }
                for (int it = 0; it < kneed; ++it) {
                    double bv = sV; int bl = lane;
#pragma unroll
                    for (int off = 1; off < 64; off <<= 1) {
                        double ov = __shfl_xor(bv, off);
                        int    ol = __shfl_xor(bl, off);
                        if (ov > bv || (ov == bv && ol < bl)) { bv = ov; bl = ol; }
                    }
                    int wsrc = __shfl(sSrc, bl);
                    if (lane == (wsrc & 63)) selmask |= 1u << (wsrc >> 6);
                    if (lane == bl) sV = -2.0;
                }
            }
        }

        // ---- write selection bits (m only; mirror derived at read time)
#pragma unroll
        for (int q = 0; q < 8; ++q) {
            if ((selmask >> q) & 1u) {
                int m = (q << 6) | lane;           // 1..511
                atomicOr(&selw[(c << 4) | (m >> 5)], 1u << (m & 31));
            }
        }
    } else {
        // waves 2,3: Hermitian unpack spP -> X0[k], X1[k] (k = 0..511) in xunp
        const int t2 = tid - 128;                  // 0..127
#pragma unroll
        for (int j = 0; j < 4; ++j) {
            int k = t2 + (j << 7);                 // 0..511
            int n = (1024 - k) & 1023;
            float2 Pk = spP[PAD16(k)];
            float2 Pn = spP[PAD16(n)];
            xunp[k]       = float2{ 0.5f * (Pk.x + Pn.x), 0.5f * (Pk.y - Pn.y) };   // X0[k]
            xunp[512 + k] = float2{ 0.5f * (Pk.y + Pn.y), 0.5f * (Pn.x - Pk.x) };   // X1[k]
        }
    }
    __syncthreads();                                   // barrier 3

    // ---- FFT 2 (inverse via conjugation), masked spectrum generated on the fly
    fft1024_z(xunp, selw, twF, lane, w, ar, ai);

    // ---- write y: out0 = Re(R)/1024, out1 = -Im(R)/1024; duplicate t<256 to t+1024
    {
        const float S = 1.0f / 1024.0f;
        float2* o2 = reinterpret_cast<float2*>(out + (size_t)b * OUT_T * DM + d0);
#pragma unroll
        for (int q = 0; q < 4; ++q) {
            int t = ((w << 2) | q) + (krev << 4);
            float2 o{ ar[q] * S, -ai[q] * S };
            o2[(size_t)t * 128] = o;
            if (t < PRED_LEN) o2[(size_t)(t + T_LEN) * 128] = o;
        }
    }
}

extern "C" void kernel_launch(void* const* d_in, const int* in_sizes, int n_in,
                              void* d_out, int out_size, void* d_ws, size_t ws_size,
                              hipStream_t stream) {
    const float* x = (const float*)d_in[0];
    float* out = (float*)d_out;
    hipLaunchKernelGGL(fl_fused_kernel, dim3(1024), dim3(256), 0, stream, x, out);
}